// Round 1
// baseline (245.911 us; speedup 1.0000x reference)
//
#include <hip/hip_runtime.h>
#include <math.h>

#define R_NODES 1152
#define DIGITS 10
#define OUT_CH 16
#define IN_CH 8
#define BATCH 256
#define COLS 160            // DIGITS*OUT_CH
#define W_PER_R 1280        // DIGITS*OUT_CH*IN_CH
#define RUNITS 72           // 1152/16
#define RCH 8               // r-rows staged in LDS at a time

// ---------- softmax over d of blog[r][10] -> c ; also zeroes sq ----------
__global__ void k_softmax(const float* __restrict__ blog,
                          float* __restrict__ c,
                          float* __restrict__ sq)
{
    if (blockIdx.x == 0 && threadIdx.x == 0) *sq = 0.f;
    int r = blockIdx.x * blockDim.x + threadIdx.x;
    if (r >= R_NODES) return;
    float v[DIGITS];
    float m = -1e30f;
#pragma unroll
    for (int d = 0; d < DIGITS; ++d) { v[d] = blog[r*DIGITS + d]; m = fmaxf(m, v[d]); }
    float ssum = 0.f;
#pragma unroll
    for (int d = 0; d < DIGITS; ++d) { v[d] = expf(v[d] - m); ssum += v[d]; }
    float inv = 1.f / ssum;
#pragma unroll
    for (int d = 0; d < DIGITS; ++d) c[r*DIGITS + d] = v[d] * inv;
}

// ---------- s partials: s[b,col] = sum_{r,i} (c[r,d]*W[r,col,i]) * u[b,r,i] ----------
// grid (nsplit, 4): blockIdx.x = K-split (16 r per unit, ups units), blockIdx.y = 64-batch block
// 256 threads = 16 colgroups (g: cols g*10..g*10+9) x 16 b-subgroups (bs: 4 b's each)
__global__ __launch_bounds__(256) void k_s(
    const float* __restrict__ u,      // [B][R][8]
    const float* __restrict__ W,      // [R][10][16][8]
    const float* __restrict__ c,      // [R][10]
    float* __restrict__ part,         // [nsplit][B][160]
    int ups)
{
    __shared__ float wt[RCH * COLS * 10];   // [r_l][col][pad-stride 10] = 12800 floats

    const int split = blockIdx.x;
    const int b0 = blockIdx.y * 64;
    const int t = threadIdx.x;
    const int g = t & 15;
    const int bs = t >> 4;

    float acc[4][10];
#pragma unroll
    for (int jj = 0; jj < 4; ++jj)
#pragma unroll
        for (int j = 0; j < 10; ++j) acc[jj][j] = 0.f;

    int u0 = split * ups;
    int u1 = u0 + ups; if (u1 > RUNITS) u1 = RUNITS;

    for (int un = u0; un < u1; ++un) {
        for (int ch = 0; ch < 2; ++ch) {
            const int r0 = un * 16 + ch * RCH;
            __syncthreads();
            // ---- stage Wc into LDS (8 r-rows = 10240 floats, coalesced float4) ----
            const float* Wg = W + (size_t)r0 * W_PER_R;
            const float* cg = c + r0 * DIGITS;
#pragma unroll
            for (int p = 0; p < 10; ++p) {
                int e4 = t + p * 256;           // float4 index 0..2559
                int e  = e4 * 4;
                int r_l = e4 / 320;
                int rem = e - r_l * W_PER_R;
                int col = rem >> 3;
                int i0  = e & 7;                // 0 or 4
                float4 w4 = *(const float4*)(Wg + e);
                float cv = cg[r_l * DIGITS + (col >> 4)];
                float2* dst = (float2*)&wt[r_l*1600 + col*10 + i0];
                dst[0] = make_float2(w4.x*cv, w4.y*cv);
                dst[1] = make_float2(w4.z*cv, w4.w*cv);
            }
            __syncthreads();
            // ---- compute: u read from global (L1-broadcast across g lanes) ----
            for (int r_l = 0; r_l < RCH; ++r_l) {
                float uu[4][8];
#pragma unroll
                for (int jj = 0; jj < 4; ++jj) {
                    const float* up = u + (size_t)(b0 + bs*4 + jj) * (R_NODES*IN_CH)
                                        + (size_t)(r0 + r_l) * IN_CH;
                    float4 a0 = *(const float4*)up;
                    float4 a1 = *(const float4*)(up + 4);
                    uu[jj][0]=a0.x; uu[jj][1]=a0.y; uu[jj][2]=a0.z; uu[jj][3]=a0.w;
                    uu[jj][4]=a1.x; uu[jj][5]=a1.y; uu[jj][6]=a1.z; uu[jj][7]=a1.w;
                }
                const float* wrow = &wt[r_l*1600 + g*100];
#pragma unroll
                for (int j = 0; j < 10; ++j) {
                    const float2* wp = (const float2*)(wrow + j*10);
                    float2 w01 = wp[0], w23 = wp[1], w45 = wp[2], w67 = wp[3];
#pragma unroll
                    for (int jj = 0; jj < 4; ++jj) {
                        float a = acc[jj][j];
                        a = fmaf(w01.x, uu[jj][0], a);
                        a = fmaf(w01.y, uu[jj][1], a);
                        a = fmaf(w23.x, uu[jj][2], a);
                        a = fmaf(w23.y, uu[jj][3], a);
                        a = fmaf(w45.x, uu[jj][4], a);
                        a = fmaf(w45.y, uu[jj][5], a);
                        a = fmaf(w67.x, uu[jj][6], a);
                        a = fmaf(w67.y, uu[jj][7], a);
                        acc[jj][j] = a;
                    }
                }
            }
        }
    }
    // deterministic partial write (no atomics)
    float* pp = part + (size_t)split * (BATCH*COLS) + (size_t)b0 * COLS;
#pragma unroll
    for (int jj = 0; jj < 4; ++jj) {
        float* row = pp + (size_t)(bs*4 + jj) * COLS + g * 10;
#pragma unroll
        for (int j = 0; j < 10; ++j) row[j] = acc[jj][j];
    }
}

// ---------- reduce partials -> s ; accumulate global sum of squares ----------
__global__ void k_sq(const float* __restrict__ part,
                     float* __restrict__ s,
                     float* __restrict__ sq, int nsplit)
{
    int e = blockIdx.x * 256 + threadIdx.x;   // grid = 160 blocks, exact
    float v = 0.f;
    for (int sp = 0; sp < nsplit; ++sp)
        v += part[(size_t)sp * (BATCH*COLS) + e];
    s[e] = v;
    float x = v * v;
#pragma unroll
    for (int off = 32; off > 0; off >>= 1)
        x += __shfl_down(x, off, 64);
    __shared__ float red[4];
    int w = threadIdx.x >> 6;
    if ((threadIdx.x & 63) == 0) red[w] = x;
    __syncthreads();
    if (threadIdx.x == 0)
        atomicAdd(sq, red[0] + red[1] + red[2] + red[3]);
}

// ---------- agreement update: blog[r,d] += scale * sum_{b,o} u_hat[b,r,d,o]*s[b,d,o] ----------
// scale = sqrt(sq)/(1+sq) factored out of v = s*scale.
// grid (144, 2): 8 r-rows per block, batch halves. 256 thr = 8 r_l x 32 lanes.
// Each lane owns 5 (d,o) pairs: p = tt + 32k  (o = tt&15, d = (tt>>4)+2k); W held in regs.
__global__ __launch_bounds__(256) void k_a(
    const float* __restrict__ u,
    const float* __restrict__ W,
    const float* __restrict__ s,
    const float* __restrict__ sq,
    float* __restrict__ blog)
{
    const int r = blockIdx.x * RCH + (threadIdx.x >> 5);
    const int tt = threadIdx.x & 31;
    const int bstart = blockIdx.y * 128;

    float wreg[5][8];
#pragma unroll
    for (int k = 0; k < 5; ++k) {
        int p = tt + 32*k;
        const float* wp = W + (size_t)r * W_PER_R + (size_t)p * IN_CH;
#pragma unroll
        for (int i = 0; i < 8; ++i) wreg[k][i] = wp[i];
    }
    float acc[5] = {0.f, 0.f, 0.f, 0.f, 0.f};
    for (int b = bstart; b < bstart + 128; ++b) {
        const float* up = u + ((size_t)b * R_NODES + r) * IN_CH;
        float4 a0 = *(const float4*)up;
        float4 a1 = *(const float4*)(up + 4);
        const float* sp = s + (size_t)b * COLS;
#pragma unroll
        for (int k = 0; k < 5; ++k) {
            float vv = sp[tt + 32*k];
            float uh;
            uh = wreg[k][0] * a0.x;
            uh = fmaf(wreg[k][1], a0.y, uh);
            uh = fmaf(wreg[k][2], a0.z, uh);
            uh = fmaf(wreg[k][3], a0.w, uh);
            uh = fmaf(wreg[k][4], a1.x, uh);
            uh = fmaf(wreg[k][5], a1.y, uh);
            uh = fmaf(wreg[k][6], a1.z, uh);
            uh = fmaf(wreg[k][7], a1.w, uh);
            acc[k] = fmaf(uh, vv, acc[k]);
        }
    }
    float q = *sq;
    float scale = sqrtf(q) / (1.f + q);
#pragma unroll
    for (int k = 0; k < 5; ++k) {
        float x = acc[k] * scale;
        x += __shfl_xor(x, 1, 64);
        x += __shfl_xor(x, 2, 64);
        x += __shfl_xor(x, 4, 64);
        x += __shfl_xor(x, 8, 64);
        if ((tt & 15) == 0) {
            int d = (tt >> 4) + 2*k;
            atomicAdd(&blog[r*DIGITS + d], x);
        }
    }
}

// ---------- final output: v = s * sqrt(sq)/(1+sq) ----------
__global__ void k_scale(const float* __restrict__ s,
                        const float* __restrict__ sq,
                        float* __restrict__ out)
{
    int e = blockIdx.x * 256 + threadIdx.x;
    float q = *sq;
    float scale = sqrtf(q) / (1.f + q);
    out[e] = s[e] * scale;
}

extern "C" void kernel_launch(void* const* d_in, const int* in_sizes, int n_in,
                              void* d_out, int out_size, void* d_ws, size_t ws_size,
                              hipStream_t stream)
{
    const float* u = (const float*)d_in[0];   // (256, 1152, 8)
    const float* W = (const float*)d_in[1];   // (1, 1152, 10, 16, 8)
    float* out = (float*)d_out;               // (256, 10, 16)
    float* ws = (float*)d_ws;

    float* blog = ws;                  // 11520 floats
    float* c    = ws + 11520;          // 11520
    float* s    = ws + 23040;          // 40960
    float* sq   = ws + 64000;          // 1 (padded)
    float* part = ws + 64064;          // nsplit * 40960

    long long ws_fl = (long long)(ws_size / 4);
    long long avail = ws_fl - 64064;
    int nsplit = (int)(avail / (BATCH * COLS));
    if (nsplit > RUNITS) nsplit = RUNITS;
    if (nsplit < 1) nsplit = 1;
    int ups = (RUNITS + nsplit - 1) / nsplit;

    hipMemsetAsync(blog, 0, 11520 * sizeof(float), stream);

    for (int it = 0; it < 3; ++it) {
        k_softmax<<<dim3((R_NODES + 255) / 256), dim3(256), 0, stream>>>(blog, c, sq);
        k_s<<<dim3(nsplit, 4), dim3(256), 0, stream>>>(u, W, c, part, ups);
        k_sq<<<dim3(BATCH * COLS / 256), dim3(256), 0, stream>>>(part, s, sq, nsplit);
        if (it < 2)
            k_a<<<dim3(R_NODES / RCH, 2), dim3(256), 0, stream>>>(u, W, s, sq, blog);
        else
            k_scale<<<dim3(BATCH * COLS / 256), dim3(256), 0, stream>>>(s, sq, out);
    }
}

// Round 2
// 199.177 us; speedup vs baseline: 1.2346x; 1.2346x over previous
//
#include <hip/hip_runtime.h>
#include <math.h>

#define R_NODES 1152
#define DIGITS 10
#define OUT_CH 16
#define IN_CH 8
#define BATCH 256
#define COLS 160            // DIGITS*OUT_CH
#define W_PER_R 1280        // DIGITS*OUT_CH*IN_CH
#define RUNITS 72           // 1152/16
#define RCH 8               // r-rows staged in LDS at a time

// ---------- softmax over d of blog[r][10] -> c ; also zeroes sq ----------
__global__ void k_softmax(const float* __restrict__ blog,
                          float* __restrict__ c,
                          float* __restrict__ sq)
{
    if (blockIdx.x == 0 && threadIdx.x == 0) *sq = 0.f;
    int r = blockIdx.x * blockDim.x + threadIdx.x;
    if (r >= R_NODES) return;
    float v[DIGITS];
    float m = -1e30f;
#pragma unroll
    for (int d = 0; d < DIGITS; ++d) { v[d] = blog[r*DIGITS + d]; m = fmaxf(m, v[d]); }
    float ssum = 0.f;
#pragma unroll
    for (int d = 0; d < DIGITS; ++d) { v[d] = expf(v[d] - m); ssum += v[d]; }
    float inv = 1.f / ssum;
#pragma unroll
    for (int d = 0; d < DIGITS; ++d) c[r*DIGITS + d] = v[d] * inv;
}

// ---------- s partials: s[b,col] = sum_{r,i} (c[r,d]*W[r,col,i]) * u[b,r,i] ----------
// grid (nsplit, 8): blockIdx.x = K-split (16 r per unit, ups units), blockIdx.y = 32-batch block
// 256 threads = 16 colgroups (g: cols g*10..g*10+9) x 16 b-subgroups (bs: 2 b's each)
__global__ __launch_bounds__(256) void k_s(
    const float* __restrict__ u,      // [B][R][8]
    const float* __restrict__ W,      // [R][10][16][8]
    const float* __restrict__ c,      // [R][10]
    float* __restrict__ part,         // [nsplit][B][160]
    int ups)
{
    __shared__ float wt[RCH * COLS * 10];   // [r_l][col][pad-stride 10] = 12800 floats

    const int split = blockIdx.x;
    const int b0 = blockIdx.y * 32;
    const int t = threadIdx.x;
    const int g = t & 15;
    const int bs = t >> 4;

    float acc[2][10];
#pragma unroll
    for (int jj = 0; jj < 2; ++jj)
#pragma unroll
        for (int j = 0; j < 10; ++j) acc[jj][j] = 0.f;

    int u0 = split * ups;
    int u1 = u0 + ups; if (u1 > RUNITS) u1 = RUNITS;

    for (int un = u0; un < u1; ++un) {
        for (int ch = 0; ch < 2; ++ch) {
            const int r0 = un * 16 + ch * RCH;
            __syncthreads();
            // ---- stage Wc into LDS (8 r-rows = 10240 floats, coalesced float4) ----
            const float* Wg = W + (size_t)r0 * W_PER_R;
            const float* cg = c + r0 * DIGITS;
#pragma unroll
            for (int p = 0; p < 10; ++p) {
                int e4 = t + p * 256;           // float4 index 0..2559
                int e  = e4 * 4;
                int r_l = e4 / 320;
                int rem = e - r_l * W_PER_R;
                int col = rem >> 3;
                int i0  = e & 7;                // 0 or 4
                float4 w4 = *(const float4*)(Wg + e);
                float cv = cg[r_l * DIGITS + (col >> 4)];
                float2* dst = (float2*)&wt[r_l*1600 + col*10 + i0];
                dst[0] = make_float2(w4.x*cv, w4.y*cv);
                dst[1] = make_float2(w4.z*cv, w4.w*cv);
            }
            __syncthreads();
            // ---- compute: u read from global (L1-broadcast across g lanes) ----
            for (int r_l = 0; r_l < RCH; ++r_l) {
                float uu[2][8];
#pragma unroll
                for (int jj = 0; jj < 2; ++jj) {
                    const float* up = u + (size_t)(b0 + bs*2 + jj) * (R_NODES*IN_CH)
                                        + (size_t)(r0 + r_l) * IN_CH;
                    float4 a0 = *(const float4*)up;
                    float4 a1 = *(const float4*)(up + 4);
                    uu[jj][0]=a0.x; uu[jj][1]=a0.y; uu[jj][2]=a0.z; uu[jj][3]=a0.w;
                    uu[jj][4]=a1.x; uu[jj][5]=a1.y; uu[jj][6]=a1.z; uu[jj][7]=a1.w;
                }
                const float* wrow = &wt[r_l*1600 + g*100];
#pragma unroll
                for (int j = 0; j < 10; ++j) {
                    const float2* wp = (const float2*)(wrow + j*10);
                    float2 w01 = wp[0], w23 = wp[1], w45 = wp[2], w67 = wp[3];
#pragma unroll
                    for (int jj = 0; jj < 2; ++jj) {
                        float a = acc[jj][j];
                        a = fmaf(w01.x, uu[jj][0], a);
                        a = fmaf(w01.y, uu[jj][1], a);
                        a = fmaf(w23.x, uu[jj][2], a);
                        a = fmaf(w23.y, uu[jj][3], a);
                        a = fmaf(w45.x, uu[jj][4], a);
                        a = fmaf(w45.y, uu[jj][5], a);
                        a = fmaf(w67.x, uu[jj][6], a);
                        a = fmaf(w67.y, uu[jj][7], a);
                        acc[jj][j] = a;
                    }
                }
            }
        }
    }
    // deterministic partial write (no atomics)
    float* pp = part + (size_t)split * (BATCH*COLS) + (size_t)b0 * COLS;
#pragma unroll
    for (int jj = 0; jj < 2; ++jj) {
        float* row = pp + (size_t)(bs*2 + jj) * COLS + g * 10;
#pragma unroll
        for (int j = 0; j < 10; ++j) row[j] = acc[jj][j];
    }
}

// ---------- reduce partials -> s ; accumulate global sum of squares ----------
__global__ void k_sq(const float* __restrict__ part,
                     float* __restrict__ s,
                     float* __restrict__ sq, int nsplit)
{
    int e = blockIdx.x * 256 + threadIdx.x;   // grid = 160 blocks, exact
    float v = 0.f;
    for (int sp = 0; sp < nsplit; ++sp)
        v += part[(size_t)sp * (BATCH*COLS) + e];
    s[e] = v;
    float x = v * v;
#pragma unroll
    for (int off = 32; off > 0; off >>= 1)
        x += __shfl_down(x, off, 64);
    __shared__ float red[4];
    int w = threadIdx.x >> 6;
    if ((threadIdx.x & 63) == 0) red[w] = x;
    __syncthreads();
    if (threadIdx.x == 0)
        atomicAdd(sq, red[0] + red[1] + red[2] + red[3]);
}

// ---------- agreement update: blog[r,d] += scale * sum_{b,o} u_hat[b,r,d,o]*s[b,d,o] ----------
// scale = sqrt(sq)/(1+sq) factored out of v = s*scale.
// grid (144, 8): 8 r-rows per block, 32 batches per block. 256 thr = 8 r_l x 32 lanes.
// Each lane owns 5 (d,o) pairs: p = tt + 32k  (o = tt&15, d = (tt>>4)+2k); W held in regs.
__global__ __launch_bounds__(256) void k_a(
    const float* __restrict__ u,
    const float* __restrict__ W,
    const float* __restrict__ s,
    const float* __restrict__ sq,
    float* __restrict__ blog)
{
    const int r = blockIdx.x * RCH + (threadIdx.x >> 5);
    const int tt = threadIdx.x & 31;
    const int bstart = blockIdx.y * 32;

    float wreg[5][8];
#pragma unroll
    for (int k = 0; k < 5; ++k) {
        int p = tt + 32*k;
        const float* wp = W + (size_t)r * W_PER_R + (size_t)p * IN_CH;
#pragma unroll
        for (int i = 0; i < 8; ++i) wreg[k][i] = wp[i];
    }
    float acc[5] = {0.f, 0.f, 0.f, 0.f, 0.f};
    for (int b = bstart; b < bstart + 32; ++b) {
        const float* up = u + ((size_t)b * R_NODES + r) * IN_CH;
        float4 a0 = *(const float4*)up;
        float4 a1 = *(const float4*)(up + 4);
        const float* sp = s + (size_t)b * COLS;
#pragma unroll
        for (int k = 0; k < 5; ++k) {
            float vv = sp[tt + 32*k];
            float uh;
            uh = wreg[k][0] * a0.x;
            uh = fmaf(wreg[k][1], a0.y, uh);
            uh = fmaf(wreg[k][2], a0.z, uh);
            uh = fmaf(wreg[k][3], a0.w, uh);
            uh = fmaf(wreg[k][4], a1.x, uh);
            uh = fmaf(wreg[k][5], a1.y, uh);
            uh = fmaf(wreg[k][6], a1.z, uh);
            uh = fmaf(wreg[k][7], a1.w, uh);
            acc[k] = fmaf(uh, vv, acc[k]);
        }
    }
    float q = *sq;
    float scale = sqrtf(q) / (1.f + q);
#pragma unroll
    for (int k = 0; k < 5; ++k) {
        float x = acc[k] * scale;
        x += __shfl_xor(x, 1, 64);
        x += __shfl_xor(x, 2, 64);
        x += __shfl_xor(x, 4, 64);
        x += __shfl_xor(x, 8, 64);
        if ((tt & 15) == 0) {
            int d = (tt >> 4) + 2*k;
            atomicAdd(&blog[r*DIGITS + d], x);
        }
    }
}

// ---------- final output: v = s * sqrt(sq)/(1+sq) ----------
__global__ void k_scale(const float* __restrict__ s,
                        const float* __restrict__ sq,
                        float* __restrict__ out)
{
    int e = blockIdx.x * 256 + threadIdx.x;
    float q = *sq;
    float scale = sqrtf(q) / (1.f + q);
    out[e] = s[e] * scale;
}

extern "C" void kernel_launch(void* const* d_in, const int* in_sizes, int n_in,
                              void* d_out, int out_size, void* d_ws, size_t ws_size,
                              hipStream_t stream)
{
    const float* u = (const float*)d_in[0];   // (256, 1152, 8)
    const float* W = (const float*)d_in[1];   // (1, 1152, 10, 16, 8)
    float* out = (float*)d_out;               // (256, 10, 16)
    float* ws = (float*)d_ws;

    float* blog = ws;                  // 11520 floats
    float* c    = ws + 11520;          // 11520
    float* s    = ws + 23040;          // 40960
    float* sq   = ws + 64000;          // 1 (padded)
    float* part = ws + 64064;          // nsplit * 40960

    long long ws_fl = (long long)(ws_size / 4);
    long long avail = ws_fl - 64064;
    int nsplit = (int)(avail / (BATCH * COLS));
    if (nsplit > RUNITS) nsplit = RUNITS;
    if (nsplit < 1) nsplit = 1;
    int ups = (RUNITS + nsplit - 1) / nsplit;

    hipMemsetAsync(blog, 0, 11520 * sizeof(float), stream);

    for (int it = 0; it < 3; ++it) {
        k_softmax<<<dim3((R_NODES + 255) / 256), dim3(256), 0, stream>>>(blog, c, sq);
        k_s<<<dim3(nsplit, 8), dim3(256), 0, stream>>>(u, W, c, part, ups);
        k_sq<<<dim3(BATCH * COLS / 256), dim3(256), 0, stream>>>(part, s, sq, nsplit);
        if (it < 2)
            k_a<<<dim3(R_NODES / RCH, 8), dim3(256), 0, stream>>>(u, W, s, sq, blog);
        else
            k_scale<<<dim3(BATCH * COLS / 256), dim3(256), 0, stream>>>(s, sq, out);
    }
}